// Round 8
// baseline (195.194 us; speedup 1.0000x reference)
//
#include <hip/hip_runtime.h>

#define DSZ 96
#define CIN 16
#define NF  16
#define NXT 12
#define NYT 12
#define NZT 6

typedef __attribute__((ext_vector_type(8))) short short8;   // 8 bf16
typedef __attribute__((ext_vector_type(4))) float f32x4;    // MFMA C/D

union I4S8 { int4 i; short8 s; };

// ---------------- prepass: pack w into 15 B-fragments ----------------
// Lane layout (validated R2-R6): k = ((l>>4)&1)*8 + j + (l>>5)*16;
// f = l&15. tp = l>>5 selects the k-half.
//  g in 0..8   : B01(dx*3+dy=g)  — tp half has tap (g, dz=tp)
//  g in 9..11  : B2mix(dx=g-9)   — tp half has tap (dx, dy=tp, dz=2)
//  g in 12..14 : B2end(dx=g-12)  — tp0: tap (dx, 2, 2); tp1: ZERO
__global__ void pack_w(const float* __restrict__ w, short* __restrict__ wpack) {
  const int g = blockIdx.x;   // 0..14
  const int l = threadIdx.x;  // 0..63
  const int tp = l >> 5;
  const int cib = ((l >> 4) & 1) * 8;
  const int f = l & 15;
  int tap;
  bool zero = false;
  if (g < 9) {
    tap = g * 3 + tp;                       // dz = tp
  } else if (g < 12) {
    tap = ((g - 9) * 3 + tp) * 3 + 2;       // dy = tp, dz = 2
  } else {
    tap = ((g - 12) * 3 + 2) * 3 + 2;       // dy = 2, dz = 2
    zero = (tp == 1);
  }
  short v[8];
#pragma unroll
  for (int j = 0; j < 8; ++j) {
    float x = zero ? 0.0f : w[(tap * 16 + cib + j) * 16 + f];
    unsigned u = __float_as_uint(x);
    u = (u + 0x7FFFu + ((u >> 16) & 1u)) >> 16;  // RNE to bf16
    v[j] = (short)u;
  }
  short8 s;
#pragma unroll
  for (int j = 0; j < 8; ++j) s[j] = v[j];
  reinterpret_cast<short8*>(wpack)[g * 64 + l] = s;
}

// ---------------- main: output-stationary LDS MFMA conv ----------------
// Block = 512 threads (8 waves) = 8x8 xy columns x 16 z outputs (R6 geom).
// Wave cx=wid holds acc[8] (all cy) and streams 30 columns: per column two
// ds_read_b128 (A01, Amix) feed up to 5 MFMAs into 3 different acc slots.
// 60 reads + 120 MFMA per strip (vs 112+112 in R6).
__global__ __launch_bounds__(512, 4) void conv_mfma_lds(
    const float* __restrict__ feat, const int* __restrict__ index,
    const float* __restrict__ bias, const short8* __restrict__ wpack,
    float* __restrict__ out) {
  __shared__ short smem[101 * 288];   // 58176 B; col 100 = zeroed pad (Amix tp1 overrun)

  const int tid = threadIdx.x;
  const int lane = tid & 63;
  const int wid = tid >> 6;

  // XCD-aware bijective swizzle (3456 % 8 == 0, chunk 432); yt fastest.
  const int d = blockIdx.x;
  int L = (d & 7) * 432 + (d >> 3);
  const int yt = L % NYT;  L /= NYT;
  const int zt = L % NZT;  L /= NZT;
  const int xt = L % NXT;
  const int b  = L / NXT;
  const int x0 = xt * 8, y0 = yt * 8, z0 = zt * 16;

  // B fragments resident (60 VGPRs).
  short8 bw[15];
#pragma unroll
  for (int t = 0; t < 15; ++t) bw[t] = wpack[t * 64 + lane];

  // ---- stage: 100 cols x 18 z-lines, f32 -> bf16 (R6-validated) ----
  for (int it = tid; it < 1800; it += 512) {
    const int col = it / 18;
    const int zp  = it - col * 18;
    const int colx = col / 10;
    const int coly = col - colx * 10;
    const int gx = x0 + colx - 1, gy = y0 + coly - 1, gz = z0 + zp - 1;
    const bool ok = ((unsigned)gx < (unsigned)DSZ) &
                    ((unsigned)gy < (unsigned)DSZ) &
                    ((unsigned)gz < (unsigned)DSZ);
    const long off = ok ? ((long)(((b * DSZ + gx) * DSZ + gy) * DSZ + gz) * CIN) : 0;
    const float4* p = reinterpret_cast<const float4*>(feat + off);
    float4 q0 = p[0], q1 = p[1], q2 = p[2], q3 = p[3];
    unsigned m0 = __builtin_amdgcn_perm(__float_as_uint(q0.y), __float_as_uint(q0.x), 0x07060302u);
    unsigned m1 = __builtin_amdgcn_perm(__float_as_uint(q0.w), __float_as_uint(q0.z), 0x07060302u);
    unsigned m2 = __builtin_amdgcn_perm(__float_as_uint(q1.y), __float_as_uint(q1.x), 0x07060302u);
    unsigned m3 = __builtin_amdgcn_perm(__float_as_uint(q1.w), __float_as_uint(q1.z), 0x07060302u);
    unsigned m4 = __builtin_amdgcn_perm(__float_as_uint(q2.y), __float_as_uint(q2.x), 0x07060302u);
    unsigned m5 = __builtin_amdgcn_perm(__float_as_uint(q2.w), __float_as_uint(q2.z), 0x07060302u);
    unsigned m6 = __builtin_amdgcn_perm(__float_as_uint(q3.y), __float_as_uint(q3.x), 0x07060302u);
    unsigned m7 = __builtin_amdgcn_perm(__float_as_uint(q3.w), __float_as_uint(q3.z), 0x07060302u);
    if (!ok) { m0 = m1 = m2 = m3 = m4 = m5 = m6 = m7 = 0u; }
    const int byte0 = (col * 576 + zp * 32) ^ ((zp & 4) << 2);
    *reinterpret_cast<int4*>((char*)smem + byte0)        = make_int4(m0, m1, m2, m3);
    *reinterpret_cast<int4*>((char*)smem + (byte0 ^ 16)) = make_int4(m4, m5, m6, m7);
  }
  // zero the pad column (finite data; B=0 halves would still NaN-poison on NaN*0)
  if (tid < 36)
    *reinterpret_cast<int4*>((char*)smem + 100 * 576 + tid * 16) =
        make_int4(0, 0, 0, 0);

  // ---- per-lane fragment bases ----
  const int r = lane & 15, h16v = lane & 16, tp = lane >> 5;
  const int zp01 = r + tp;                                   // 0..16
  const int pre01 = (zp01 * 32 + h16v) ^ ((zp01 & 4) << 2);  // A01: dz = tp
  const int zpm = r + 2;                                     // 2..17
  const int preMx = ((zpm * 32 + h16v) ^ ((zpm & 4) << 2)) + tp * 576;  // Amix: col += tp
  const int cx = wid;
  const int base01 = pre01 + cx * 5760;
  const int baseMx = preMx + cx * 5760;

  const int fq = lane & 15, hq = lane >> 4;
  const float bf = bias[fq];
  const char* smb = (const char*)smem;

  f32x4 acc[8];
#pragma unroll
  for (int cy = 0; cy < 8; ++cy) acc[cy] = f32x4{0.f, 0.f, 0.f, 0.f};

  __syncthreads();

  // ---- compute: stream 30 columns, 5 MFMA max each, all offsets immediate --
#pragma unroll
  for (int dx = 0; dx < 3; ++dx) {
#pragma unroll
    for (int yc = 0; yc < 10; ++yc) {
      const int o = dx * 5760 + yc * 576;
      I4S8 a01, amx;
      a01.i = *reinterpret_cast<const int4*>(smb + base01 + o);
      amx.i = *reinterpret_cast<const int4*>(smb + baseMx + o);
      if (yc <= 7)
        acc[yc]     = __builtin_amdgcn_mfma_f32_16x16x32_bf16(a01.s, bw[dx * 3 + 0], acc[yc], 0, 0, 0);
      if (yc >= 1 && yc <= 8)
        acc[yc - 1] = __builtin_amdgcn_mfma_f32_16x16x32_bf16(a01.s, bw[dx * 3 + 1], acc[yc - 1], 0, 0, 0);
      if (yc >= 2)
        acc[yc - 2] = __builtin_amdgcn_mfma_f32_16x16x32_bf16(a01.s, bw[dx * 3 + 2], acc[yc - 2], 0, 0, 0);
      if (yc <= 7)
        acc[yc]     = __builtin_amdgcn_mfma_f32_16x16x32_bf16(amx.s, bw[9 + dx],  acc[yc], 0, 0, 0);
      if (yc >= 2)
        acc[yc - 2] = __builtin_amdgcn_mfma_f32_16x16x32_bf16(amx.s, bw[12 + dx], acc[yc - 2], 0, 0, 0);
    }
  }

  // ---- epilogue: +bias, mask by index, store f32 ----
  const int vbase0 = ((b * DSZ + (x0 + cx)) * DSZ + y0) * DSZ + z0;
#pragma unroll
  for (int cy = 0; cy < 8; ++cy) {
    const int vb = vbase0 + cy * DSZ;
    const int4 iv = *reinterpret_cast<const int4*>(index + vb + hq * 4);
    float* op = out + (long)(vb + hq * 4) * NF + fq;
    op[0 * NF] = iv.x ? (acc[cy][0] + bf) : 0.0f;
    op[1 * NF] = iv.y ? (acc[cy][1] + bf) : 0.0f;
    op[2 * NF] = iv.z ? (acc[cy][2] + bf) : 0.0f;
    op[3 * NF] = iv.w ? (acc[cy][3] + bf) : 0.0f;
  }
}

// ---------------- fallback (tiny ws): round-1 f32 kernel ----------------
__global__ __launch_bounds__(256) void sparse_conv_f32(
    const float* __restrict__ feat, const int* __restrict__ index,
    const float* __restrict__ w, const float* __restrict__ bias,
    float* __restrict__ out) {
  const int v = blockIdx.x * 256 + threadIdx.x;
  const int z = v % DSZ;
  int t = v / DSZ;
  const int y = t % DSZ; t /= DSZ;
  const int x = t % DSZ;
  const int bb = t / DSZ;
  float acc[NF];
#pragma unroll
  for (int f = 0; f < NF; ++f) acc[f] = bias[f];
  const bool active = (index[v] != 0);
#pragma unroll 1
  for (int kx = -1; kx <= 1; ++kx) {
    const int xx = x + kx;
    const bool okx = ((unsigned)xx < (unsigned)DSZ);
#pragma unroll 1
    for (int ky = -1; ky <= 1; ++ky) {
      const int yy = y + ky;
      const bool oky = okx && ((unsigned)yy < (unsigned)DSZ);
#pragma unroll 1
      for (int kz = -1; kz <= 1; ++kz) {
        const int zz = z + kz;
        const bool ok = oky && ((unsigned)zz < (unsigned)DSZ);
        const long long off = ((((long long)bb * DSZ + xx) * DSZ + yy) * DSZ + zz) * CIN;
        float4 q0, q1, q2, q3;
        if (ok) {
          const float4* fp = reinterpret_cast<const float4*>(feat + off);
          q0 = fp[0]; q1 = fp[1]; q2 = fp[2]; q3 = fp[3];
        } else {
          q0 = q1 = q2 = q3 = make_float4(0.f, 0.f, 0.f, 0.f);
        }
        const float fv[CIN] = {q0.x, q0.y, q0.z, q0.w, q1.x, q1.y, q1.z, q1.w,
                               q2.x, q2.y, q2.z, q2.w, q3.x, q3.y, q3.z, q3.w};
        const float* wr = w + ((((kx + 1) * 3 + (ky + 1)) * 3 + (kz + 1)) * CIN) * NF;
#pragma unroll
        for (int ci = 0; ci < CIN; ++ci) {
          const float fvv = fv[ci];
#pragma unroll
          for (int f = 0; f < NF; ++f) acc[f] = fmaf(fvv, wr[ci * NF + f], acc[f]);
        }
      }
    }
  }
  float4* op = reinterpret_cast<float4*>(out + (long long)v * NF);
  if (active) {
    op[0] = make_float4(acc[0], acc[1], acc[2], acc[3]);
    op[1] = make_float4(acc[4], acc[5], acc[6], acc[7]);
    op[2] = make_float4(acc[8], acc[9], acc[10], acc[11]);
    op[3] = make_float4(acc[12], acc[13], acc[14], acc[15]);
  } else {
    const float4 z4 = make_float4(0.f, 0.f, 0.f, 0.f);
    op[0] = z4; op[1] = z4; op[2] = z4; op[3] = z4;
  }
}

extern "C" void kernel_launch(void* const* d_in, const int* in_sizes, int n_in,
                              void* d_out, int out_size, void* d_ws, size_t ws_size,
                              hipStream_t stream) {
  const float* feat  = (const float*)d_in[0];
  const int*   index = (const int*)d_in[1];
  const float* w     = (const float*)d_in[2];
  const float* bias  = (const float*)d_in[3];
  float*       out   = (float*)d_out;

  const int nvox = in_sizes[1];  // 4*96*96*96

  if (ws_size < 15 * 64 * 8 * sizeof(short)) {
    sparse_conv_f32<<<nvox / 256, 256, 0, stream>>>(feat, index, w, bias, out);
    return;
  }

  short* wpack = (short*)d_ws;
  pack_w<<<15, 64, 0, stream>>>(w, wpack);

  const int blocks = 4 * NXT * NYT * NZT;  // 3456
  conv_mfma_lds<<<blocks, 512, 0, stream>>>(feat, index, bias,
                                            (const short8*)wpack, out);
}

// Round 9
// 137.761 us; speedup vs baseline: 1.4169x; 1.4169x over previous
//
#include <hip/hip_runtime.h>

#define DSZ 96
#define CIN 16
#define NF  16
#define NXT 12
#define NYT 12
#define NZT 6

typedef __attribute__((ext_vector_type(8))) short short8;   // 8 bf16
typedef __attribute__((ext_vector_type(4))) float f32x4;    // MFMA C/D

union I4S8 { int4 i; short8 s; };

// ---------------- prepass: pack w into 15 B-fragments ----------------
// Lane layout (validated R2-R8): k = ((l>>4)&1)*8 + j + (l>>5)*16;
// f = l&15. tp = l>>5 selects the k-half.
//  g in 0..8   : B01(dx*3+dy=g)  — tp half has tap (g, dz=tp)
//  g in 9..11  : B2mix(dx=g-9)   — tp half has tap (dx, dy=tp, dz=2)
//  g in 12..14 : B2end(dx=g-12)  — tp0: tap (dx, 2, 2); tp1: ZERO
__global__ void pack_w(const float* __restrict__ w, short* __restrict__ wpack) {
  const int g = blockIdx.x;   // 0..14
  const int l = threadIdx.x;  // 0..63
  const int tp = l >> 5;
  const int cib = ((l >> 4) & 1) * 8;
  const int f = l & 15;
  int tap;
  bool zero = false;
  if (g < 9) {
    tap = g * 3 + tp;                       // dz = tp
  } else if (g < 12) {
    tap = ((g - 9) * 3 + tp) * 3 + 2;       // dy = tp, dz = 2
  } else {
    tap = ((g - 12) * 3 + 2) * 3 + 2;       // dy = 2, dz = 2
    zero = (tp == 1);
  }
  short v[8];
#pragma unroll
  for (int j = 0; j < 8; ++j) {
    float x = zero ? 0.0f : w[(tap * 16 + cib + j) * 16 + f];
    unsigned u = __float_as_uint(x);
    u = (u + 0x7FFFu + ((u >> 16) & 1u)) >> 16;  // RNE to bf16
    v[j] = (short)u;
  }
  short8 s;
#pragma unroll
  for (int j = 0; j < 8; ++j) s[j] = v[j];
  reinterpret_cast<short8*>(wpack)[g * 64 + l] = s;
}

// ---------------- main: output-stationary LDS MFMA conv ----------------
// Block = 512 threads (8 waves) = 8x8 xy columns x 16 z outputs.
// Wave cx=wid holds acc[8] (all cy) and streams 30 columns: per column two
// ds_read_b128 (A01, Amix) feed up to 5 MFMAs into 3 different acc slots.
// 60 reads + 120 MFMA per strip (vs 112+112 in R6).
// launch_bounds(512,2): R8's (,4) capped the allocator at 64 VGPRs and
// spilled acc[8] (WRITE +183MB); LDS already limits to 2 blocks/CU, so
// promise only 2 waves/EU and let bw[15]+acc[8] live in registers.
__global__ __launch_bounds__(512, 2) void conv_mfma_lds(
    const float* __restrict__ feat, const int* __restrict__ index,
    const float* __restrict__ bias, const short8* __restrict__ wpack,
    float* __restrict__ out) {
  __shared__ short smem[101 * 288];   // 58176 B; col 100 = zeroed pad (Amix tp1 overrun)

  const int tid = threadIdx.x;
  const int lane = tid & 63;
  const int wid = tid >> 6;

  // XCD-aware bijective swizzle (3456 % 8 == 0, chunk 432); yt fastest.
  const int d = blockIdx.x;
  int L = (d & 7) * 432 + (d >> 3);
  const int yt = L % NYT;  L /= NYT;
  const int zt = L % NZT;  L /= NZT;
  const int xt = L % NXT;
  const int b  = L / NXT;
  const int x0 = xt * 8, y0 = yt * 8, z0 = zt * 16;

  // B fragments resident (60 VGPRs).
  short8 bw[15];
#pragma unroll
  for (int t = 0; t < 15; ++t) bw[t] = wpack[t * 64 + lane];

  // ---- stage: 100 cols x 18 z-lines, f32 -> bf16 (R6-validated) ----
  for (int it = tid; it < 1800; it += 512) {
    const int col = it / 18;
    const int zp  = it - col * 18;
    const int colx = col / 10;
    const int coly = col - colx * 10;
    const int gx = x0 + colx - 1, gy = y0 + coly - 1, gz = z0 + zp - 1;
    const bool ok = ((unsigned)gx < (unsigned)DSZ) &
                    ((unsigned)gy < (unsigned)DSZ) &
                    ((unsigned)gz < (unsigned)DSZ);
    const long off = ok ? ((long)(((b * DSZ + gx) * DSZ + gy) * DSZ + gz) * CIN) : 0;
    const float4* p = reinterpret_cast<const float4*>(feat + off);
    float4 q0 = p[0], q1 = p[1], q2 = p[2], q3 = p[3];
    unsigned m0 = __builtin_amdgcn_perm(__float_as_uint(q0.y), __float_as_uint(q0.x), 0x07060302u);
    unsigned m1 = __builtin_amdgcn_perm(__float_as_uint(q0.w), __float_as_uint(q0.z), 0x07060302u);
    unsigned m2 = __builtin_amdgcn_perm(__float_as_uint(q1.y), __float_as_uint(q1.x), 0x07060302u);
    unsigned m3 = __builtin_amdgcn_perm(__float_as_uint(q1.w), __float_as_uint(q1.z), 0x07060302u);
    unsigned m4 = __builtin_amdgcn_perm(__float_as_uint(q2.y), __float_as_uint(q2.x), 0x07060302u);
    unsigned m5 = __builtin_amdgcn_perm(__float_as_uint(q2.w), __float_as_uint(q2.z), 0x07060302u);
    unsigned m6 = __builtin_amdgcn_perm(__float_as_uint(q3.y), __float_as_uint(q3.x), 0x07060302u);
    unsigned m7 = __builtin_amdgcn_perm(__float_as_uint(q3.w), __float_as_uint(q3.z), 0x07060302u);
    if (!ok) { m0 = m1 = m2 = m3 = m4 = m5 = m6 = m7 = 0u; }
    const int byte0 = (col * 576 + zp * 32) ^ ((zp & 4) << 2);
    *reinterpret_cast<int4*>((char*)smem + byte0)        = make_int4(m0, m1, m2, m3);
    *reinterpret_cast<int4*>((char*)smem + (byte0 ^ 16)) = make_int4(m4, m5, m6, m7);
  }
  // zero the pad column (Amix tp1 overrun must multiply finite zeros)
  if (tid < 36)
    *reinterpret_cast<int4*>((char*)smem + 100 * 576 + tid * 16) =
        make_int4(0, 0, 0, 0);

  // ---- per-lane fragment bases ----
  const int r = lane & 15, h16v = lane & 16, tp = lane >> 5;
  const int zp01 = r + tp;                                   // 0..16
  const int pre01 = (zp01 * 32 + h16v) ^ ((zp01 & 4) << 2);  // A01: dz = tp
  const int zpm = r + 2;                                     // 2..17
  const int preMx = ((zpm * 32 + h16v) ^ ((zpm & 4) << 2)) + tp * 576;  // Amix: col += tp
  const int cx = wid;
  const int base01 = pre01 + cx * 5760;
  const int baseMx = preMx + cx * 5760;

  const int fq = lane & 15, hq = lane >> 4;
  const float bf = bias[fq];
  const char* smb = (const char*)smem;

  f32x4 acc[8];
#pragma unroll
  for (int cy = 0; cy < 8; ++cy) acc[cy] = f32x4{0.f, 0.f, 0.f, 0.f};

  __syncthreads();

  // ---- compute: stream 30 columns, 5 MFMA max each, all offsets immediate --
#pragma unroll
  for (int dx = 0; dx < 3; ++dx) {
#pragma unroll
    for (int yc = 0; yc < 10; ++yc) {
      const int o = dx * 5760 + yc * 576;
      I4S8 a01, amx;
      a01.i = *reinterpret_cast<const int4*>(smb + base01 + o);
      amx.i = *reinterpret_cast<const int4*>(smb + baseMx + o);
      if (yc <= 7)
        acc[yc]     = __builtin_amdgcn_mfma_f32_16x16x32_bf16(a01.s, bw[dx * 3 + 0], acc[yc], 0, 0, 0);
      if (yc >= 1 && yc <= 8)
        acc[yc - 1] = __builtin_amdgcn_mfma_f32_16x16x32_bf16(a01.s, bw[dx * 3 + 1], acc[yc - 1], 0, 0, 0);
      if (yc >= 2)
        acc[yc - 2] = __builtin_amdgcn_mfma_f32_16x16x32_bf16(a01.s, bw[dx * 3 + 2], acc[yc - 2], 0, 0, 0);
      if (yc <= 7)
        acc[yc]     = __builtin_amdgcn_mfma_f32_16x16x32_bf16(amx.s, bw[9 + dx],  acc[yc], 0, 0, 0);
      if (yc >= 2)
        acc[yc - 2] = __builtin_amdgcn_mfma_f32_16x16x32_bf16(amx.s, bw[12 + dx], acc[yc - 2], 0, 0, 0);
    }
  }

  // ---- epilogue: +bias, mask by index, store f32 ----
  const int vbase0 = ((b * DSZ + (x0 + cx)) * DSZ + y0) * DSZ + z0;
#pragma unroll
  for (int cy = 0; cy < 8; ++cy) {
    const int vb = vbase0 + cy * DSZ;
    const int4 iv = *reinterpret_cast<const int4*>(index + vb + hq * 4);
    float* op = out + (long)(vb + hq * 4) * NF + fq;
    op[0 * NF] = iv.x ? (acc[cy][0] + bf) : 0.0f;
    op[1 * NF] = iv.y ? (acc[cy][1] + bf) : 0.0f;
    op[2 * NF] = iv.z ? (acc[cy][2] + bf) : 0.0f;
    op[3 * NF] = iv.w ? (acc[cy][3] + bf) : 0.0f;
  }
}

// ---------------- fallback (tiny ws): round-1 f32 kernel ----------------
__global__ __launch_bounds__(256) void sparse_conv_f32(
    const float* __restrict__ feat, const int* __restrict__ index,
    const float* __restrict__ w, const float* __restrict__ bias,
    float* __restrict__ out) {
  const int v = blockIdx.x * 256 + threadIdx.x;
  const int z = v % DSZ;
  int t = v / DSZ;
  const int y = t % DSZ; t /= DSZ;
  const int x = t % DSZ;
  const int bb = t / DSZ;
  float acc[NF];
#pragma unroll
  for (int f = 0; f < NF; ++f) acc[f] = bias[f];
  const bool active = (index[v] != 0);
#pragma unroll 1
  for (int kx = -1; kx <= 1; ++kx) {
    const int xx = x + kx;
    const bool okx = ((unsigned)xx < (unsigned)DSZ);
#pragma unroll 1
    for (int ky = -1; ky <= 1; ++ky) {
      const int yy = y + ky;
      const bool oky = okx && ((unsigned)yy < (unsigned)DSZ);
#pragma unroll 1
      for (int kz = -1; kz <= 1; ++kz) {
        const int zz = z + kz;
        const bool ok = oky && ((unsigned)zz < (unsigned)DSZ);
        const long long off = ((((long long)bb * DSZ + xx) * DSZ + yy) * DSZ + zz) * CIN;
        float4 q0, q1, q2, q3;
        if (ok) {
          const float4* fp = reinterpret_cast<const float4*>(feat + off);
          q0 = fp[0]; q1 = fp[1]; q2 = fp[2]; q3 = fp[3];
        } else {
          q0 = q1 = q2 = q3 = make_float4(0.f, 0.f, 0.f, 0.f);
        }
        const float fv[CIN] = {q0.x, q0.y, q0.z, q0.w, q1.x, q1.y, q1.z, q1.w,
                               q2.x, q2.y, q2.z, q2.w, q3.x, q3.y, q3.z, q3.w};
        const float* wr = w + ((((kx + 1) * 3 + (ky + 1)) * 3 + (kz + 1)) * CIN) * NF;
#pragma unroll
        for (int ci = 0; ci < CIN; ++ci) {
          const float fvv = fv[ci];
#pragma unroll
          for (int f = 0; f < NF; ++f) acc[f] = fmaf(fvv, wr[ci * NF + f], acc[f]);
        }
      }
    }
  }
  float4* op = reinterpret_cast<float4*>(out + (long long)v * NF);
  if (active) {
    op[0] = make_float4(acc[0], acc[1], acc[2], acc[3]);
    op[1] = make_float4(acc[4], acc[5], acc[6], acc[7]);
    op[2] = make_float4(acc[8], acc[9], acc[10], acc[11]);
    op[3] = make_float4(acc[12], acc[13], acc[14], acc[15]);
  } else {
    const float4 z4 = make_float4(0.f, 0.f, 0.f, 0.f);
    op[0] = z4; op[1] = z4; op[2] = z4; op[3] = z4;
  }
}

extern "C" void kernel_launch(void* const* d_in, const int* in_sizes, int n_in,
                              void* d_out, int out_size, void* d_ws, size_t ws_size,
                              hipStream_t stream) {
  const float* feat  = (const float*)d_in[0];
  const int*   index = (const int*)d_in[1];
  const float* w     = (const float*)d_in[2];
  const float* bias  = (const float*)d_in[3];
  float*       out   = (float*)d_out;

  const int nvox = in_sizes[1];  // 4*96*96*96

  if (ws_size < 15 * 64 * 8 * sizeof(short)) {
    sparse_conv_f32<<<nvox / 256, 256, 0, stream>>>(feat, index, w, bias, out);
    return;
  }

  short* wpack = (short*)d_ws;
  pack_w<<<15, 64, 0, stream>>>(w, wpack);

  const int blocks = 4 * NXT * NYT * NZT;  // 3456
  conv_mfma_lds<<<blocks, 512, 0, stream>>>(feat, index, bias,
                                            (const short8*)wpack, out);
}